// Round 6
// baseline (12408.220 us; speedup 1.0000x reference)
//
#include <hip/hip_runtime.h>
#include <math.h>

#define NIN 64
#define NHID 128
#define NOUT 64

typedef __bf16 bf16x8 __attribute__((ext_vector_type(8)));
typedef float  floatx4 __attribute__((ext_vector_type(4)));

__device__ __forceinline__ float sigmoidf(float x){ return 1.0f/(1.0f+expf(-x)); }
__device__ __forceinline__ float b2f_lo(unsigned p){ unsigned b = p<<16; return __uint_as_float(b); }
__device__ __forceinline__ float b2f_hi(unsigned p){ unsigned b = p & 0xffff0000u; return __uint_as_float(b); }
__device__ __forceinline__ unsigned f2pk(float lo, float hi){
  __bf16 a=(__bf16)lo, b=(__bf16)hi;
  unsigned short ua, ub;
  __builtin_memcpy(&ua,&a,2); __builtin_memcpy(&ub,&b,2);
  return (unsigned)ua | ((unsigned)ub<<16);
}

// ---------------- precompute: degree, dinv, CSR ----------------
__global__ void k_deg_init(int* __restrict__ deg, int n){
  int v = blockIdx.x*256 + threadIdx.x;
  if(v<n) deg[v] = 1;
}
__global__ void k_deg_count(const int* __restrict__ dst, int E, int* __restrict__ deg){
  int e = blockIdx.x*256 + threadIdx.x;
  if(e<E) atomicAdd(&deg[dst[e]], 1);
}
__global__ void k_dinv(const int* __restrict__ deg, float* __restrict__ dinv, int n){
  int v = blockIdx.x*256 + threadIdx.x;
  if(v<n) dinv[v] = rsqrtf((float)deg[v]);
}
__global__ __launch_bounds__(1024) void k_scan(const int* __restrict__ deg,
    int* __restrict__ row_ptr, int* __restrict__ fill, int n){
  __shared__ int lds[1024];
  __shared__ int s_carry;
  if(threadIdx.x==0) s_carry=0;
  __syncthreads();
  int nchunk=(n+1023)/1024;
  for(int ch=0; ch<nchunk; ++ch){
    int v = ch*1024 + threadIdx.x;
    int val = (v<n)? (deg[v]-1) : 0;
    lds[threadIdx.x]=val;
    __syncthreads();
    for(int off=1; off<1024; off<<=1){
      int t=(threadIdx.x>=off)? lds[threadIdx.x-off] : 0;
      __syncthreads();
      lds[threadIdx.x]+=t;
      __syncthreads();
    }
    int incl=lds[threadIdx.x];
    int carry=s_carry;
    if(v<n){ row_ptr[v]=carry+incl-val; fill[v]=carry+incl-val; }
    __syncthreads();
    if(threadIdx.x==1023) s_carry=carry+lds[1023];
    __syncthreads();
  }
  if(threadIdx.x==0) row_ptr[n]=s_carry;
}
__global__ void k_fill(const int* __restrict__ src, const int* __restrict__ dst, int E,
                       int* __restrict__ fill, int* __restrict__ ecol){
  int e = blockIdx.x*256 + threadIdx.x;
  if(e<E){
    int d = dst[e];
    int pos = atomicAdd(&fill[d], 1);
    ecol[pos] = src[e];
  }
}

// ---------------- weight prep ----------------
__global__ void k_prep_wb(const float* __restrict__ Wi, const float* __restrict__ Wf,
                          const float* __restrict__ Wo, const float* __restrict__ Wg,
                          __bf16* __restrict__ Wb){
  int idx = blockIdx.x*256 + threadIdx.x;
  if(idx >= 32*6*64*8) return;
  int jj = idx & 7;
  int L  = (idx >> 3) & 63;
  int t  = idx >> 9;
  int kt = t - (t/6)*6, CT = t/6;
  int colj = CT*16 + (L & 15);
  int k    = kt*32 + ((L >> 4) << 3) + jj;
  int gate = colj >> 7, jg = colj & 127;
  const float* W = (gate==0)? Wi : (gate==1)? Wf : (gate==2)? Wo : Wg;
  Wb[idx] = (__bf16)W[jg*192 + k];
}
__global__ void k_prep_w1(const float* __restrict__ W1, float* __restrict__ W1t){
  int idx = blockIdx.x*256 + threadIdx.x;
  if(idx >= 128*256) return;
  int k = idx >> 8, j = idx & 255;
  W1t[idx] = (j<128)? W1[j*256+k] : W1[(j-128)*256+128+k];
}
__global__ void k_prep_wc(const float* __restrict__ Wc, float* __restrict__ Wct){
  int idx = blockIdx.x*256 + threadIdx.x;
  if(idx >= 128*64) return;
  int k = idx/64, j = idx%64;
  Wct[idx] = Wc[j*128+k];
}

// ------- init: zero h (both bufs incl ghost row) + xs ghost rows + barrier --
__global__ void k_init(unsigned* __restrict__ hpA, unsigned* __restrict__ hpB,
                       __bf16* __restrict__ xs, unsigned* __restrict__ bar,
                       int NP, int T){
  int i = blockIdx.x*256 + threadIdx.x;
  if(i < (NP+1)*64){ hpA[i]=0u; hpB[i]=0u; }
  if(i < T*64){ int t=i>>6, f=i&63; xs[((size_t)t*(NP+1) + NP)*64 + f] = (__bf16)0.f; }
  if(i < 128) bar[i]=0u;
}

// ---------------- xs = dinv[v] * x, bf16, layout [T][NP+1][64] ------------
// vectorized: 1 thread = 8 elems (32B load, 16B store)  [R1-verified]
__global__ void k_xscale(const float* __restrict__ x, const float* __restrict__ dinv,
                         __bf16* __restrict__ xs, int n, int NP){
  int i = blockIdx.x*256 + threadIdx.x;      // index of 8-float group
  if(i >= n*8) return;
  int t = blockIdx.y;
  float dv = dinv[i>>3];
  const float4* xp = (const float4*)(x + (size_t)t*(size_t)n*64) + (size_t)i*2;
  float4 a = xp[0], b = xp[1];
  bf16x8 o;
  o[0]=(__bf16)(a.x*dv); o[1]=(__bf16)(a.y*dv); o[2]=(__bf16)(a.z*dv); o[3]=(__bf16)(a.w*dv);
  o[4]=(__bf16)(b.x*dv); o[5]=(__bf16)(b.y*dv); o[6]=(__bf16)(b.z*dv); o[7]=(__bf16)(b.w*dv);
  *(bf16x8*)(xs + ((size_t)t*(NP+1))*64 + (size_t)i*8) = o;
}

// ---------- manual device-scope grid barrier (sense = step index) ----------
// Arrive: release fence + agent-scope atomicAdd. Last block bumps gen.
// Wait: agent-scope acquire loads on gen. Safe under normal (non-coop)
// launch because grid(512) == co-residency capacity (2 blocks/CU forced by
// __launch_bounds__(512,4) VGPR cap 128, LDS ~15KB).
__device__ __forceinline__ void gbar(unsigned* cnt, unsigned* gen, int nblk, unsigned g){
  __syncthreads();
  if(threadIdx.x==0){
    __threadfence();   // release: flush this block's h writes toward IF$
    unsigned a=__hip_atomic_fetch_add(cnt,1u,__ATOMIC_ACQ_REL,__HIP_MEMORY_SCOPE_AGENT);
    if(a==(unsigned)(nblk-1)){
      __hip_atomic_store(cnt,0u,__ATOMIC_RELAXED,__HIP_MEMORY_SCOPE_AGENT);
      __hip_atomic_store(gen,g+1u,__ATOMIC_RELEASE,__HIP_MEMORY_SCOPE_AGENT);
    }else{
      unsigned cur;
      do{
        __builtin_amdgcn_s_sleep(4);
        cur=__hip_atomic_load(gen,__ATOMIC_ACQUIRE,__HIP_MEMORY_SCOPE_AGENT);
      }while((int)(cur-(g+1u))<0);
    }
    __threadfence();   // acquire: invalidate stale L1/L2 before next gathers
  }
  __syncthreads();
}

// ---------- persistent fused step loop: ALL 64 steps in one kernel --------
// R0-proven inner geometry (512 thr = 8 waves, 2 nodes/wave gather, same
// MFMA fragment mapping). Persistence wins: CSR/meta/s_col loaded ONCE,
// c-state in registers (no cbuf traffic), no per-step launch/dispatch/tail.
// Block b owns tiles {b, b+gridDim.x}; one shared s_a reused across tiles.
__global__ __launch_bounds__(512,4) void k_steps(
    const __bf16* __restrict__ xs,         // [T][NP+1][64] pre-scaled
    unsigned* __restrict__ hpA,            // [NP+1][64] packed h (2 bf16/word)
    unsigned* __restrict__ hpB,
    float* __restrict__ hbuf,              // [NP][128] final-step h
    const int* __restrict__ row_ptr, const int* __restrict__ ecol,
    const float* __restrict__ dinv, const __bf16* __restrict__ Wb,
    const float* __restrict__ bi, const float* __restrict__ bf_,
    const float* __restrict__ bo, const float* __restrict__ bg,
    unsigned* __restrict__ bar_cnt, unsigned* __restrict__ bar_gen,
    int n, int NP, int T, int ntiles)
{
  __shared__ __align__(16) __bf16 s_a[6*544];
  __shared__ int   s_col[2][1024];
  __shared__ int   s_deg[2][16];
  __shared__ int   s_beg[2][16];
  __shared__ float s_dv[2][16];
  const int tid=threadIdx.x, wv=tid>>6, l=tid&63;
  const int l15=l&15, quad=l>>4;
  const int nblk = gridDim.x;

  // ---- one-time setup: tile meta + ELL columns for both owned tiles ----
  int tileid[2]; tileid[0]=blockIdx.x; tileid[1]=blockIdx.x+nblk;
  #pragma unroll
  for(int p=0;p<2;++p){
    if(tid<16){
      int tile=tileid[p];
      int v = tile*16+tid;
      bool val = (tile<ntiles) && (v<n);
      int beg=val? row_ptr[v]:0, end=val? row_ptr[v+1]:0;
      s_beg[p][tid]=beg; s_deg[p][tid]=end-beg;
      s_dv[p][tid]=val? dinv[v]:0.f;
    }
  }
  __syncthreads();
  #pragma unroll
  for(int p=0;p<2;++p)
    for(int idx=tid; idx<1024; idx+=512){
      int m=idx>>6, kk=idx&63;
      s_col[p][idx]=(kk<s_deg[p][m])? ecol[s_beg[p][m]+kk] : NP; // pad->ghost
    }
  __syncthreads();

  int Kp[2]; int ov[2];
  #pragma unroll
  for(int p=0;p<2;++p){
    int d0=s_deg[p][2*wv], d1=s_deg[p][2*wv+1];
    ov[p] = (d0>64)||(d1>64);
    d0=d0>64?64:d0; d1=d1>64?64:d1;
    Kp[p]=d0>d1?d0:d1;
  }

  float creg[2][4];
  #pragma unroll
  for(int p=0;p<2;++p){
    #pragma unroll
    for(int r=0;r<4;++r) creg[p][r]=0.f;
  }

  const int jg=16*wv+l15;

  for(int t=0;t<T;++t){
    const __bf16* __restrict__ xst = xs + (size_t)t*(size_t)(NP+1)*64;
    const unsigned* __restrict__ hp = (t&1)? hpB : hpA;
    unsigned* __restrict__ hc = (t&1)? hpA : hpB;
    const int last = (t==T-1);

    #pragma unroll
    for(int p=0;p<2;++p){
      const int tile = tileid[p];
      const int v0 = tile*16;
      const bool tval = (tile<ntiles);

      // ---- phase 1: gather (self + ELL neighbors), 2 nodes per wave ----
      if(tval){
        float ax[2], alo[2], ahi[2];
        #pragma unroll
        for(int i=0;i<2;++i){
          int v=v0+2*wv+i;
          ax[i]=(float)xst[(size_t)v*64+l];
          unsigned pw=hp[(size_t)v*64+l];
          alo[i]=b2f_lo(pw); ahi[i]=b2f_hi(pw);
        }
        const int* cr=&s_col[p][(2*wv)*64];
        const int K = Kp[p];
        #pragma unroll 2
        for(int kk=0;kk<K;++kk){
          int u0=cr[kk], u1=cr[64+kk];
          float    x0=(float)xst[(size_t)u0*64+l];
          unsigned p0=hp[(size_t)u0*64+l];
          float    x1=(float)xst[(size_t)u1*64+l];
          unsigned p1=hp[(size_t)u1*64+l];
          ax[0]+=x0; alo[0]+=b2f_lo(p0); ahi[0]+=b2f_hi(p0);
          ax[1]+=x1; alo[1]+=b2f_lo(p1); ahi[1]+=b2f_hi(p1);
        }
        if(ov[p]){
          #pragma unroll
          for(int i=0;i<2;++i){               // rare deg>64 overflow
            int m=2*wv+i, d=s_deg[p][m];
            if(d>64){
              for(int e2=s_beg[p][m]+64;e2<s_beg[p][m]+d;++e2){
                int u=ecol[e2];
                ax[i]+=(float)xst[(size_t)u*64+l];
                unsigned pw=hp[(size_t)u*64+l];
                alo[i]+=b2f_lo(pw); ahi[i]+=b2f_hi(pw);
              }
            }
          }
        }
        {
          int kt0=l>>5, q0=(l>>3)&3, j0=l&7;
          int L2=2*l, kt1=2+(L2>>5), q1=(L2>>3)&3, j1=L2&7;
          #pragma unroll
          for(int i=0;i<2;++i){
            int m=2*wv+i; float dv=s_dv[p][m];
            s_a[kt0*544+q0*136+m*8+j0]=(__bf16)(dv*ax[i]);
            *(unsigned*)&s_a[kt1*544+q1*136+m*8+j1]=f2pk(dv*alo[i],dv*ahi[i]);
          }
        }
      }
      __syncthreads();

      // ---- phase 2+3: MFMA (CT = 8g+wv) + LSTM pointwise (c in regs) ----
      if(tval){
        bf16x8 af[6];
        #pragma unroll
        for(int kt=0;kt<6;++kt)
          af[kt]=*(bf16x8*)&s_a[kt*544+quad*136+l15*8];
        floatx4 acc[4];
        #pragma unroll
        for(int g=0;g<4;++g){
          const float* bsel = (g==0)? bi : (g==1)? bf_ : (g==2)? bo : bg;
          float b=bsel[jg];
          floatx4 a={b,b,b,b};
          const __bf16* bp=Wb + (size_t)((8*g+wv)*6)*512 + (size_t)l*8;
          #pragma unroll
          for(int kt=0;kt<6;++kt)
            a=__builtin_amdgcn_mfma_f32_16x16x32_bf16(af[kt],*(const bf16x8*)(bp+kt*512),a,0,0,0);
          acc[g]=a;
        }
        #pragma unroll
        for(int r=0;r<4;++r){
          int m=quad*4+r, v=v0+m;
          float I=sigmoidf(acc[0][r]);
          float F=sigmoidf(acc[1][r]);
          float O=sigmoidf(acc[2][r]);
          float G=tanhf  (acc[3][r]);
          float cn=F*creg[p][r]+I*G;
          creg[p][r]=cn;
          float hn=O*tanhf(cn);
          float hs=s_dv[p][m]*hn;
          float hs2=__shfl_xor(hs,1,64);
          if((l15&1)==0)
            hc[(size_t)v*64+(jg>>1)]=f2pk(hs,hs2);  // word w = cols {2w,2w+1}
          if(last) hbuf[(size_t)v*128+jg]=hn;
        }
      }
      __syncthreads();   // protect s_a before next tile's gather
    }
    gbar(bar_cnt, bar_gen, nblk, (unsigned)t);
  }
}

// ---------------- head (R4-verified chain) ----------------
__global__ __launch_bounds__(256) void k_head1(const float* __restrict__ h,
    const float* __restrict__ W1t, float* __restrict__ Hio, int n){
  __shared__ float s_h[16][NHID];
  int v0 = blockIdx.x*16;
  for(int i=threadIdx.x; i<16*NHID; i+=256){
    int m = i/NHID, k = i - m*NHID;
    int v = v0 + m;
    s_h[m][k] = (v<n)? h[(size_t)v*NHID + k] : 0.0f;
  }
  __syncthreads();
  int j = threadIdx.x;
  float acc[16];
  #pragma unroll
  for(int m=0;m<16;++m) acc[m]=0.f;
  for(int k=0;k<NHID;++k){
    float w = W1t[k*256 + j];
    #pragma unroll
    for(int m=0;m<16;++m) acc[m] = fmaf(w, s_h[m][k], acc[m]);
  }
  for(int m=0;m<16;++m){
    int v = v0 + m;
    if(v >= n) break;
    Hio[(size_t)v*256 + j] = acc[m];
  }
}
__global__ __launch_bounds__(256) void k_e2n(const float* __restrict__ Hio,
    const int* __restrict__ row_ptr, const int* __restrict__ col,
    const float* __restrict__ b1, float* __restrict__ nodes, int n){
  int wv = threadIdx.x >> 6, lane = threadIdx.x & 63;
  int v = blockIdx.x*4 + wv;
  if(v >= n) return;
  float base0 = Hio[(size_t)v*256 + lane]      + b1[lane];
  float base1 = Hio[(size_t)v*256 + 64 + lane] + b1[64+lane];
  float a0=0.f, a1=0.f;
  int beg=row_ptr[v], end=row_ptr[v+1];
  int e=beg;
  for(; e+1<end; e+=2){          // 2-way unroll: double the loads in flight
    int u0 = col[e], u1 = col[e+1];
    float p0 = Hio[(size_t)u0*256 + 128 + lane];
    float q0 = Hio[(size_t)u0*256 + 192 + lane];
    float p1 = Hio[(size_t)u1*256 + 128 + lane];
    float q1 = Hio[(size_t)u1*256 + 192 + lane];
    a0 += fmaxf(base0 + p0, 0.0f) + fmaxf(base0 + p1, 0.0f);
    a1 += fmaxf(base1 + q0, 0.0f) + fmaxf(base1 + q1, 0.0f);
  }
  if(e<end){
    int u = col[e];
    a0 += fmaxf(base0 + Hio[(size_t)u*256 + 128 + lane], 0.0f);
    a1 += fmaxf(base1 + Hio[(size_t)u*256 + 192 + lane], 0.0f);
  }
  nodes[(size_t)v*NHID + lane]      = a0;
  nodes[(size_t)v*NHID + 64 + lane] = a1;
}
__global__ __launch_bounds__(64) void k_head2(const float* __restrict__ nodes,
    const float* __restrict__ Wct, float* __restrict__ tmp, int n){
  __shared__ float s_n[16][NHID];
  int v0 = blockIdx.x*16;
  for(int i=threadIdx.x; i<16*NHID; i+=64){
    int m = i/NHID, k = i - m*NHID;
    int v = v0 + m;
    s_n[m][k] = (v<n)? nodes[(size_t)v*NHID + k] : 0.0f;
  }
  __syncthreads();
  int j = threadIdx.x;
  float acc[16];
  #pragma unroll
  for(int m=0;m<16;++m) acc[m]=0.f;
  for(int k=0;k<NHID;++k){
    float w = Wct[k*64 + j];
    #pragma unroll
    for(int m=0;m<16;++m) acc[m] = fmaf(w, s_n[m][k], acc[m]);
  }
  for(int m=0;m<16;++m){
    int v = v0 + m;
    if(v >= n) break;
    tmp[(size_t)v*64 + j] = acc[m];
  }
}
__global__ __launch_bounds__(256) void k_final(const float* __restrict__ tmp,
    const int* __restrict__ row_ptr, const int* __restrict__ col,
    const float* __restrict__ dinv, const float* __restrict__ bc,
    float* __restrict__ out, int n){
  int wv = threadIdx.x >> 6, lane = threadIdx.x & 63;
  int v = blockIdx.x*4 + wv;
  if(v >= n) return;
  float dv = dinv[v];
  float acc = dv*dv*tmp[(size_t)v*64 + lane];
  int beg=row_ptr[v], end=row_ptr[v+1];
  int e=beg;
  for(; e+1<end; e+=2){          // 2-way unroll
    int u0 = col[e], u1 = col[e+1];
    float d0 = dinv[u0], d1 = dinv[u1];
    float t0 = tmp[(size_t)u0*64 + lane];
    float t1 = tmp[(size_t)u1*64 + lane];
    acc = fmaf(dv*d0, t0, acc);
    acc = fmaf(dv*d1, t1, acc);
  }
  if(e<end){
    int u = col[e];
    acc = fmaf(dv*dinv[u], tmp[(size_t)u*64 + lane], acc);
  }
  out[(size_t)v*64 + lane] = acc + bc[lane];
}

extern "C" void kernel_launch(void* const* d_in, const int* in_sizes, int n_in,
                              void* d_out, int out_size, void* d_ws, size_t ws_size,
                              hipStream_t stream) {
  (void)n_in; (void)ws_size;
  const float* x  = (const float*)d_in[0];
  const int*   ei = (const int*)d_in[1];
  const float* Wi = (const float*)d_in[4];  const float* bi  = (const float*)d_in[5];
  const float* Wf = (const float*)d_in[6];  const float* bf_ = (const float*)d_in[7];
  const float* Wo = (const float*)d_in[8];  const float* bo  = (const float*)d_in[9];
  const float* Wg = (const float*)d_in[10]; const float* bg  = (const float*)d_in[11];
  const float* W1 = (const float*)d_in[12]; const float* b1  = (const float*)d_in[13];
  const float* Wc = (const float*)d_in[14]; const float* bc  = (const float*)d_in[15];
  float* out = (float*)d_out;

  const int E = in_sizes[2];
  const int n = out_size / NOUT;
  int T = in_sizes[0] / (n * NIN);
  int ntiles = (n + 15)/16;
  int NP = ntiles*16;
  const int* srcl = ei;
  const int* dstl = ei + E;

  char* p = (char*)d_ws;
  auto alloc = [&](size_t bytes){ char* r = p; p += ((bytes + 255)/256)*256; return r; };
  int*      deg     = (int*)     alloc((size_t)n*4);
  float*    dinv    = (float*)   alloc((size_t)n*4);
  int*      row_ptr = (int*)     alloc((size_t)(n+1)*4);
  int*      fill    = (int*)     alloc((size_t)n*4);
  int*      ecol    = (int*)     alloc((size_t)E*4);
  __bf16*   Wb      = (__bf16*)  alloc((size_t)32*6*64*8*2);
  float*    W1t     = (float*)   alloc((size_t)128*256*4);
  float*    Wct     = (float*)   alloc((size_t)128*64*4);
  __bf16*   xs      = (__bf16*)  alloc((size_t)T*(NP+1)*64*2);
  unsigned* hpA     = (unsigned*)alloc((size_t)(NP+1)*64*4);
  unsigned* hpB     = (unsigned*)alloc((size_t)(NP+1)*64*4);
  unsigned* bar     = (unsigned*)alloc((size_t)512);
  float*    hbuf    = (float*)   alloc((size_t)NP*128*4);
  float*    Hio     = (float*)   alloc((size_t)NP*256*4);
  float*    nodes   = (float*)   alloc((size_t)n*NHID*4);
  float*    tmp     = (float*)   alloc((size_t)NP*64*4);

  int gn = (n+255)/256;
  int gE = (E+255)/256;

  k_deg_init <<<gn, 256, 0, stream>>>(deg, n);
  k_deg_count<<<gE, 256, 0, stream>>>(dstl, E, deg);
  k_dinv     <<<gn, 256, 0, stream>>>(deg, dinv, n);
  k_scan     <<<1, 1024, 0, stream>>>(deg, row_ptr, fill, n);
  k_fill     <<<gE, 256, 0, stream>>>(srcl, dstl, E, fill, ecol);

  k_prep_wb<<<(32*6*64*8+255)/256, 256, 0, stream>>>(Wi, Wf, Wo, Wg, Wb);
  k_prep_w1<<<(128*256+255)/256, 256, 0, stream>>>(W1, W1t);
  k_prep_wc<<<(128*64+255)/256, 256, 0, stream>>>(Wc, Wct);

  k_init<<<(((NP+1)*64)+255)/256, 256, 0, stream>>>(hpA, hpB, xs, bar, NP, T);
  k_xscale<<<dim3((n*8+255)/256, T), 256, 0, stream>>>(x, dinv, xs, n, NP);

  {
    int G = 512;   // == co-residency capacity (2 blocks/CU x 256 CUs)
    k_steps<<<G, 512, 0, stream>>>(xs, hpA, hpB, hbuf, row_ptr, ecol, dinv, Wb,
                                   bi, bf_, bo, bg, bar, bar+64,
                                   n, NP, T, ntiles);
  }

  k_head1<<<ntiles, 256, 0, stream>>>(hbuf, W1t, Hio, n);
  k_e2n  <<<(n+3)/4, 256, 0, stream>>>(Hio, row_ptr, ecol, b1, nodes, n);
  k_head2<<<(n+15)/16, 64, 0, stream>>>(nodes, Wct, tmp, n);
  k_final<<<(n+3)/4, 256, 0, stream>>>(tmp, row_ptr, ecol, dinv, bc, out, n);
}

// Round 7
// 2201.562 us; speedup vs baseline: 5.6361x; 5.6361x over previous
//
#include <hip/hip_runtime.h>
#include <math.h>

#define NIN 64
#define NHID 128
#define NOUT 64

typedef __bf16 bf16x8 __attribute__((ext_vector_type(8)));
typedef float  floatx4 __attribute__((ext_vector_type(4)));

__device__ __forceinline__ float sigmoidf(float x){ return 1.0f/(1.0f+expf(-x)); }
__device__ __forceinline__ float b2f_lo(unsigned p){ unsigned b = p<<16; return __uint_as_float(b); }
__device__ __forceinline__ float b2f_hi(unsigned p){ unsigned b = p & 0xffff0000u; return __uint_as_float(b); }
__device__ __forceinline__ unsigned f2pk(float lo, float hi){
  __bf16 a=(__bf16)lo, b=(__bf16)hi;
  unsigned short ua, ub;
  __builtin_memcpy(&ua,&a,2); __builtin_memcpy(&ub,&b,2);
  return (unsigned)ua | ((unsigned)ub<<16);
}

// ---------------- precompute: degree, dinv, CSR ----------------
__global__ void k_deg_init(int* __restrict__ deg, int n){
  int v = blockIdx.x*256 + threadIdx.x;
  if(v<n) deg[v] = 1;
}
__global__ void k_deg_count(const int* __restrict__ dst, int E, int* __restrict__ deg){
  int e = blockIdx.x*256 + threadIdx.x;
  if(e<E) atomicAdd(&deg[dst[e]], 1);
}
__global__ void k_dinv(const int* __restrict__ deg, float* __restrict__ dinv, int n){
  int v = blockIdx.x*256 + threadIdx.x;
  if(v<n) dinv[v] = rsqrtf((float)deg[v]);
}
__global__ __launch_bounds__(1024) void k_scan(const int* __restrict__ deg,
    int* __restrict__ row_ptr, int* __restrict__ fill, int n){
  __shared__ int lds[1024];
  __shared__ int s_carry;
  if(threadIdx.x==0) s_carry=0;
  __syncthreads();
  int nchunk=(n+1023)/1024;
  for(int ch=0; ch<nchunk; ++ch){
    int v = ch*1024 + threadIdx.x;
    int val = (v<n)? (deg[v]-1) : 0;
    lds[threadIdx.x]=val;
    __syncthreads();
    for(int off=1; off<1024; off<<=1){
      int t=(threadIdx.x>=off)? lds[threadIdx.x-off] : 0;
      __syncthreads();
      lds[threadIdx.x]+=t;
      __syncthreads();
    }
    int incl=lds[threadIdx.x];
    int carry=s_carry;
    if(v<n){ row_ptr[v]=carry+incl-val; fill[v]=carry+incl-val; }
    __syncthreads();
    if(threadIdx.x==1023) s_carry=carry+lds[1023];
    __syncthreads();
  }
  if(threadIdx.x==0) row_ptr[n]=s_carry;
}
__global__ void k_fill(const int* __restrict__ src, const int* __restrict__ dst, int E,
                       int* __restrict__ fill, int* __restrict__ ecol){
  int e = blockIdx.x*256 + threadIdx.x;
  if(e<E){
    int d = dst[e];
    int pos = atomicAdd(&fill[d], 1);
    ecol[pos] = src[e];
  }
}

// ---------------- weight prep ----------------
__global__ void k_prep_wb(const float* __restrict__ Wi, const float* __restrict__ Wf,
                          const float* __restrict__ Wo, const float* __restrict__ Wg,
                          __bf16* __restrict__ Wb){
  int idx = blockIdx.x*256 + threadIdx.x;
  if(idx >= 32*6*64*8) return;
  int jj = idx & 7;
  int L  = (idx >> 3) & 63;
  int t  = idx >> 9;
  int kt = t - (t/6)*6, CT = t/6;
  int colj = CT*16 + (L & 15);
  int k    = kt*32 + ((L >> 4) << 3) + jj;
  int gate = colj >> 7, jg = colj & 127;
  const float* W = (gate==0)? Wi : (gate==1)? Wf : (gate==2)? Wo : Wg;
  Wb[idx] = (__bf16)W[jg*192 + k];
}
__global__ void k_prep_w1(const float* __restrict__ W1, float* __restrict__ W1t){
  int idx = blockIdx.x*256 + threadIdx.x;
  if(idx >= 128*256) return;
  int k = idx >> 8, j = idx & 255;
  W1t[idx] = (j<128)? W1[j*256+k] : W1[(j-128)*256+128+k];
}
__global__ void k_prep_wc(const float* __restrict__ Wc, float* __restrict__ Wct){
  int idx = blockIdx.x*256 + threadIdx.x;
  if(idx >= 128*64) return;
  int k = idx/64, j = idx%64;
  Wct[idx] = Wc[j*128+k];
}

// ------- init: zero h (both bufs incl ghost row), c, xs ghost rows --------
__global__ void k_init(unsigned* __restrict__ hpA, unsigned* __restrict__ hpB,
                       float* __restrict__ cbuf, __bf16* __restrict__ xs,
                       int NP, int T){
  int i = blockIdx.x*256 + threadIdx.x;
  if(i < (NP+1)*64){ hpA[i]=0u; hpB[i]=0u; }
  if(i < NP*128) cbuf[i]=0.f;
  if(i < T*64){ int t=i>>6, f=i&63; xs[((size_t)t*(NP+1) + NP)*64 + f] = (__bf16)0.f; }
}

// ---------------- xs = dinv[v] * x, bf16, layout [T][NP+1][64] ------------
// vectorized: 1 thread = 8 elems (32B load, 16B store)  [R1-verified]
__global__ void k_xscale(const float* __restrict__ x, const float* __restrict__ dinv,
                         __bf16* __restrict__ xs, int n, int NP){
  int i = blockIdx.x*256 + threadIdx.x;      // index of 8-float group
  if(i >= n*8) return;
  int t = blockIdx.y;
  float dv = dinv[i>>3];
  const float4* xp = (const float4*)(x + (size_t)t*(size_t)n*64) + (size_t)i*2;
  float4 a = xp[0], b = xp[1];
  bf16x8 o;
  o[0]=(__bf16)(a.x*dv); o[1]=(__bf16)(a.y*dv); o[2]=(__bf16)(a.z*dv); o[3]=(__bf16)(a.w*dv);
  o[4]=(__bf16)(b.x*dv); o[5]=(__bf16)(b.y*dv); o[6]=(__bf16)(b.z*dv); o[7]=(__bf16)(b.w*dv);
  *(bf16x8*)(xs + ((size_t)t*(NP+1))*64 + (size_t)i*8) = o;
}

// ---- fused step, dual-tile: 512 thr = 8 waves; block b owns tiles ----
// {b, b+gridDim.x}. R0-proven inner body (gather 2 nodes/wave, MFMA frag
// mapping, pointwise with cbuf). grid=313 <= 512 residency slots =>
// single dispatch round per step (no tail). Dual-tile scaffolding
// correctness-proven in R6 (minus fences).
__global__ __launch_bounds__(512,5) void k_step(
    const __bf16* __restrict__ xst,        // [NP+1][64] slab for step t
    const unsigned* __restrict__ hp_prev,  // [NP+1][64]
    unsigned* __restrict__ hp_cur,
    float* __restrict__ cbuf,              // [NP][128]
    float* __restrict__ hbuf,              // [NP][128] (written on last step)
    const int* __restrict__ row_ptr, const int* __restrict__ ecol,
    const float* __restrict__ dinv, const __bf16* __restrict__ Wb,
    const float* __restrict__ bi, const float* __restrict__ bf_,
    const float* __restrict__ bo, const float* __restrict__ bg,
    int n, int NP, int last, int ntiles)
{
  __shared__ __align__(16) __bf16 s_a[6*544];
  __shared__ int   s_col[2][1024];
  __shared__ int   s_deg[2][16];
  __shared__ int   s_beg[2][16];
  __shared__ float s_dv[2][16];
  const int tid=threadIdx.x, wv=tid>>6, l=tid&63;
  const int l15=l&15, quad=l>>4;
  const int G = gridDim.x;

  if(tid<32){
    int p=tid>>4, q=tid&15;
    int tile=blockIdx.x+p*G;
    int v=tile*16+q;
    bool val=(tile<ntiles)&&(v<n);
    int beg=val? row_ptr[v]:0, end=val? row_ptr[v+1]:0;
    s_beg[p][q]=beg; s_deg[p][q]=end-beg;
    s_dv[p][q]=val? dinv[v]:0.f;
  }
  __syncthreads();
  for(int idx=tid; idx<2048; idx+=512){
    int p=idx>>10, m=(idx>>6)&15, kk=idx&63;
    s_col[p][idx&1023]=(kk<s_deg[p][m])? ecol[s_beg[p][m]+kk] : NP; // pad->ghost
  }
  __syncthreads();

  const int jg=16*wv+l15;

  #pragma unroll
  for(int p=0;p<2;++p){
    const int tile = blockIdx.x+p*G;
    const int v0 = tile*16;
    const bool tval = (tile<ntiles);

    // ---- phase 1: gather (self + ELL neighbors), 2 nodes per wave ----
    if(tval){
      float ax[2], alo[2], ahi[2];
      int d0=s_deg[p][2*wv], d1=s_deg[p][2*wv+1];
      bool ovf=(d0>64)||(d1>64);
      d0=d0>64?64:d0; d1=d1>64?64:d1;
      const int K=d0>d1?d0:d1;
      #pragma unroll
      for(int i=0;i<2;++i){
        int v=v0+2*wv+i;
        ax[i]=(float)xst[(size_t)v*64+l];
        unsigned pw=hp_prev[(size_t)v*64+l];
        alo[i]=b2f_lo(pw); ahi[i]=b2f_hi(pw);
      }
      const int* cr=&s_col[p][(2*wv)*64];
      #pragma unroll 2
      for(int kk=0;kk<K;++kk){
        int u0=cr[kk], u1=cr[64+kk];
        float    x0=(float)xst[(size_t)u0*64+l];
        unsigned p0=hp_prev[(size_t)u0*64+l];
        float    x1=(float)xst[(size_t)u1*64+l];
        unsigned p1=hp_prev[(size_t)u1*64+l];
        ax[0]+=x0; alo[0]+=b2f_lo(p0); ahi[0]+=b2f_hi(p0);
        ax[1]+=x1; alo[1]+=b2f_lo(p1); ahi[1]+=b2f_hi(p1);
      }
      if(ovf){
        #pragma unroll
        for(int i=0;i<2;++i){               // rare deg>64 overflow
          int m=2*wv+i, d=s_deg[p][m];
          if(d>64){
            for(int e2=s_beg[p][m]+64;e2<s_beg[p][m]+d;++e2){
              int u=ecol[e2];
              ax[i]+=(float)xst[(size_t)u*64+l];
              unsigned pw=hp_prev[(size_t)u*64+l];
              alo[i]+=b2f_lo(pw); ahi[i]+=b2f_hi(pw);
            }
          }
        }
      }
      {
        int kt0=l>>5, q0=(l>>3)&3, j0=l&7;
        int L2=2*l, kt1=2+(L2>>5), q1=(L2>>3)&3, j1=L2&7;
        #pragma unroll
        for(int i=0;i<2;++i){
          int m=2*wv+i; float dv=s_dv[p][m];
          s_a[kt0*544+q0*136+m*8+j0]=(__bf16)(dv*ax[i]);
          *(unsigned*)&s_a[kt1*544+q1*136+m*8+j1]=f2pk(dv*alo[i],dv*ahi[i]);
        }
      }
    }
    __syncthreads();

    // ---- phase 2: MFMA; wave wv: CT = 8g+wv per gate g ----
    if(tval){
      bf16x8 af[6];
      #pragma unroll
      for(int kt=0;kt<6;++kt)
        af[kt]=*(bf16x8*)&s_a[kt*544+quad*136+l15*8];
      floatx4 acc[4];
      #pragma unroll
      for(int g=0;g<4;++g){
        const float* bsel = (g==0)? bi : (g==1)? bf_ : (g==2)? bo : bg;
        float b=bsel[jg];
        floatx4 a={b,b,b,b};
        const __bf16* bp=Wb + (size_t)((8*g+wv)*6)*512 + (size_t)l*8;
        #pragma unroll
        for(int kt=0;kt<6;++kt)
          a=__builtin_amdgcn_mfma_f32_16x16x32_bf16(af[kt],*(const bf16x8*)(bp+kt*512),a,0,0,0);
        acc[g]=a;
      }

      // ---- phase 3: LSTM pointwise in registers ----
      #pragma unroll
      for(int r=0;r<4;++r){
        int m=quad*4+r, v=v0+m;
        float I=sigmoidf(acc[0][r]);
        float F=sigmoidf(acc[1][r]);
        float O=sigmoidf(acc[2][r]);
        float Gg=tanhf (acc[3][r]);
        size_t coff=(size_t)v*128+jg;
        float cn=F*cbuf[coff]+I*Gg;
        cbuf[coff]=cn;
        float hn=O*tanhf(cn);
        float hs=s_dv[p][m]*hn;
        float hs2=__shfl_xor(hs,1,64);
        if((l15&1)==0)
          hp_cur[(size_t)v*64+(jg>>1)]=f2pk(hs,hs2);  // word w = cols {2w,2w+1}
        if(last) hbuf[coff]=hn;
      }
    }
    __syncthreads();   // protect s_a before next tile's gather
  }
}

// ---------------- head (R4-verified chain) ----------------
__global__ __launch_bounds__(256) void k_head1(const float* __restrict__ h,
    const float* __restrict__ W1t, float* __restrict__ Hio, int n){
  __shared__ float s_h[16][NHID];
  int v0 = blockIdx.x*16;
  for(int i=threadIdx.x; i<16*NHID; i+=256){
    int m = i/NHID, k = i - m*NHID;
    int v = v0 + m;
    s_h[m][k] = (v<n)? h[(size_t)v*NHID + k] : 0.0f;
  }
  __syncthreads();
  int j = threadIdx.x;
  float acc[16];
  #pragma unroll
  for(int m=0;m<16;++m) acc[m]=0.f;
  for(int k=0;k<NHID;++k){
    float w = W1t[k*256 + j];
    #pragma unroll
    for(int m=0;m<16;++m) acc[m] = fmaf(w, s_h[m][k], acc[m]);
  }
  for(int m=0;m<16;++m){
    int v = v0 + m;
    if(v >= n) break;
    Hio[(size_t)v*256 + j] = acc[m];
  }
}
__global__ __launch_bounds__(256) void k_e2n(const float* __restrict__ Hio,
    const int* __restrict__ row_ptr, const int* __restrict__ col,
    const float* __restrict__ b1, float* __restrict__ nodes, int n){
  int wv = threadIdx.x >> 6, lane = threadIdx.x & 63;
  int v = blockIdx.x*4 + wv;
  if(v >= n) return;
  float base0 = Hio[(size_t)v*256 + lane]      + b1[lane];
  float base1 = Hio[(size_t)v*256 + 64 + lane] + b1[64+lane];
  float a0=0.f, a1=0.f;
  int beg=row_ptr[v], end=row_ptr[v+1];
  int e=beg;
  for(; e+1<end; e+=2){          // 2-way unroll: double the loads in flight
    int u0 = col[e], u1 = col[e+1];
    float p0 = Hio[(size_t)u0*256 + 128 + lane];
    float q0 = Hio[(size_t)u0*256 + 192 + lane];
    float p1 = Hio[(size_t)u1*256 + 128 + lane];
    float q1 = Hio[(size_t)u1*256 + 192 + lane];
    a0 += fmaxf(base0 + p0, 0.0f) + fmaxf(base0 + p1, 0.0f);
    a1 += fmaxf(base1 + q0, 0.0f) + fmaxf(base1 + q1, 0.0f);
  }
  if(e<end){
    int u = col[e];
    a0 += fmaxf(base0 + Hio[(size_t)u*256 + 128 + lane], 0.0f);
    a1 += fmaxf(base1 + Hio[(size_t)u*256 + 192 + lane], 0.0f);
  }
  nodes[(size_t)v*NHID + lane]      = a0;
  nodes[(size_t)v*NHID + 64 + lane] = a1;
}
__global__ __launch_bounds__(64) void k_head2(const float* __restrict__ nodes,
    const float* __restrict__ Wct, float* __restrict__ tmp, int n){
  __shared__ float s_n[16][NHID];
  int v0 = blockIdx.x*16;
  for(int i=threadIdx.x; i<16*NHID; i+=64){
    int m = i/NHID, k = i - m*NHID;
    int v = v0 + m;
    s_n[m][k] = (v<n)? nodes[(size_t)v*NHID + k] : 0.0f;
  }
  __syncthreads();
  int j = threadIdx.x;
  float acc[16];
  #pragma unroll
  for(int m=0;m<16;++m) acc[m]=0.f;
  for(int k=0;k<NHID;++k){
    float w = Wct[k*64 + j];
    #pragma unroll
    for(int m=0;m<16;++m) acc[m] = fmaf(w, s_n[m][k], acc[m]);
  }
  for(int m=0;m<16;++m){
    int v = v0 + m;
    if(v >= n) break;
    tmp[(size_t)v*64 + j] = acc[m];
  }
}
__global__ __launch_bounds__(256) void k_final(const float* __restrict__ tmp,
    const int* __restrict__ row_ptr, const int* __restrict__ col,
    const float* __restrict__ dinv, const float* __restrict__ bc,
    float* __restrict__ out, int n){
  int wv = threadIdx.x >> 6, lane = threadIdx.x & 63;
  int v = blockIdx.x*4 + wv;
  if(v >= n) return;
  float dv = dinv[v];
  float acc = dv*dv*tmp[(size_t)v*64 + lane];
  int beg=row_ptr[v], end=row_ptr[v+1];
  int e=beg;
  for(; e+1<end; e+=2){          // 2-way unroll
    int u0 = col[e], u1 = col[e+1];
    float d0 = dinv[u0], d1 = dinv[u1];
    float t0 = tmp[(size_t)u0*64 + lane];
    float t1 = tmp[(size_t)u1*64 + lane];
    acc = fmaf(dv*d0, t0, acc);
    acc = fmaf(dv*d1, t1, acc);
  }
  if(e<end){
    int u = col[e];
    acc = fmaf(dv*dinv[u], tmp[(size_t)u*64 + lane], acc);
  }
  out[(size_t)v*64 + lane] = acc + bc[lane];
}

extern "C" void kernel_launch(void* const* d_in, const int* in_sizes, int n_in,
                              void* d_out, int out_size, void* d_ws, size_t ws_size,
                              hipStream_t stream) {
  (void)n_in; (void)ws_size;
  const float* x  = (const float*)d_in[0];
  const int*   ei = (const int*)d_in[1];
  const float* Wi = (const float*)d_in[4];  const float* bi  = (const float*)d_in[5];
  const float* Wf = (const float*)d_in[6];  const float* bf_ = (const float*)d_in[7];
  const float* Wo = (const float*)d_in[8];  const float* bo  = (const float*)d_in[9];
  const float* Wg = (const float*)d_in[10]; const float* bg  = (const float*)d_in[11];
  const float* W1 = (const float*)d_in[12]; const float* b1  = (const float*)d_in[13];
  const float* Wc = (const float*)d_in[14]; const float* bc  = (const float*)d_in[15];
  float* out = (float*)d_out;

  const int E = in_sizes[2];
  const int n = out_size / NOUT;
  const int T = in_sizes[0] / (n * NIN);
  const int ntiles = (n + 15)/16;
  const int NP = ntiles*16;
  const int* srcl = ei;
  const int* dstl = ei + E;

  char* p = (char*)d_ws;
  auto alloc = [&](size_t bytes){ char* r = p; p += ((bytes + 255)/256)*256; return r; };
  int*      deg     = (int*)     alloc((size_t)n*4);
  float*    dinv    = (float*)   alloc((size_t)n*4);
  int*      row_ptr = (int*)     alloc((size_t)(n+1)*4);
  int*      fill    = (int*)     alloc((size_t)n*4);
  int*      ecol    = (int*)     alloc((size_t)E*4);
  __bf16*   Wb      = (__bf16*)  alloc((size_t)32*6*64*8*2);
  float*    W1t     = (float*)   alloc((size_t)128*256*4);
  float*    Wct     = (float*)   alloc((size_t)128*64*4);
  __bf16*   xs      = (__bf16*)  alloc((size_t)T*(NP+1)*64*2);
  unsigned* hpA     = (unsigned*)alloc((size_t)(NP+1)*64*4);
  unsigned* hpB     = (unsigned*)alloc((size_t)(NP+1)*64*4);
  float*    cbuf    = (float*)   alloc((size_t)NP*128*4);
  float*    hbuf    = (float*)   alloc((size_t)NP*128*4);
  float*    Hio     = (float*)   alloc((size_t)NP*256*4);
  float*    nodes   = (float*)   alloc((size_t)n*NHID*4);
  float*    tmp     = (float*)   alloc((size_t)NP*64*4);

  int gn = (n+255)/256;
  int gE = (E+255)/256;

  k_deg_init <<<gn, 256, 0, stream>>>(deg, n);
  k_deg_count<<<gE, 256, 0, stream>>>(dstl, E, deg);
  k_dinv     <<<gn, 256, 0, stream>>>(deg, dinv, n);
  k_scan     <<<1, 1024, 0, stream>>>(deg, row_ptr, fill, n);
  k_fill     <<<gE, 256, 0, stream>>>(srcl, dstl, E, fill, ecol);

  k_prep_wb<<<(32*6*64*8+255)/256, 256, 0, stream>>>(Wi, Wf, Wo, Wg, Wb);
  k_prep_w1<<<(128*256+255)/256, 256, 0, stream>>>(W1, W1t);
  k_prep_wc<<<(128*64+255)/256, 256, 0, stream>>>(Wc, Wct);

  k_init<<<((NP*128)+255)/256, 256, 0, stream>>>(hpA, hpB, cbuf, xs, NP, T);
  k_xscale<<<dim3((n*8+255)/256, T), 256, 0, stream>>>(x, dinv, xs, n, NP);

  {
    const int G = (ntiles+1)/2;   // dual-tile: 313 blocks <= 512 slots
    for(int t=0; t<T; ++t){
      const __bf16* xst = xs + (size_t)t*(size_t)(NP+1)*64;
      const unsigned* hp = (t & 1)? hpB : hpA;
      unsigned*       hc = (t & 1)? hpA : hpB;
      k_step<<<G, 512, 0, stream>>>(xst, hp, hc, cbuf, hbuf, row_ptr, ecol, dinv,
                                    Wb, bi, bf_, bo, bg, n, NP, (t==T-1)?1:0, ntiles);
    }
  }

  k_head1<<<ntiles, 256, 0, stream>>>(hbuf, W1t, Hio, n);
  k_e2n  <<<(n+3)/4, 256, 0, stream>>>(Hio, row_ptr, ecol, b1, nodes, n);
  k_head2<<<(n+15)/16, 64, 0, stream>>>(nodes, Wct, tmp, n);
  k_final<<<(n+3)/4, 256, 0, stream>>>(tmp, row_ptr, ecol, dinv, bc, out, n);
}

// Round 8
// 1567.837 us; speedup vs baseline: 7.9142x; 1.4042x over previous
//
#include <hip/hip_runtime.h>
#include <math.h>

#define NIN 64
#define NHID 128
#define NOUT 64

typedef __bf16 bf16x8 __attribute__((ext_vector_type(8)));
typedef float  floatx4 __attribute__((ext_vector_type(4)));

// branch-free fast transcendentals (v_exp_f32 + v_rcp_f32 path).
// limits: fsig(+inf)=1, fsig(-inf)=0, ftanh(+inf)=1, ftanh(-inf)=-1.
__device__ __forceinline__ float fsig(float x){
  return __fdividef(1.0f, 1.0f + __expf(-x));
}
__device__ __forceinline__ float ftanh(float x){
  return 1.0f - 2.0f*__fdividef(1.0f, 1.0f + __expf(2.0f*x));
}
__device__ __forceinline__ float b2f_lo(unsigned p){ unsigned b = p<<16; return __uint_as_float(b); }
__device__ __forceinline__ float b2f_hi(unsigned p){ unsigned b = p & 0xffff0000u; return __uint_as_float(b); }
__device__ __forceinline__ unsigned f2pk(float lo, float hi){
  __bf16 a=(__bf16)lo, b=(__bf16)hi;
  unsigned short ua, ub;
  __builtin_memcpy(&ua,&a,2); __builtin_memcpy(&ub,&b,2);
  return (unsigned)ua | ((unsigned)ub<<16);
}

// ---------------- precompute: degree, dinv, CSR ----------------
__global__ void k_deg_init(int* __restrict__ deg, int n){
  int v = blockIdx.x*256 + threadIdx.x;
  if(v<n) deg[v] = 1;
}
__global__ void k_deg_count(const int* __restrict__ dst, int E, int* __restrict__ deg){
  int e = blockIdx.x*256 + threadIdx.x;
  if(e<E) atomicAdd(&deg[dst[e]], 1);
}
__global__ void k_dinv(const int* __restrict__ deg, float* __restrict__ dinv, int n){
  int v = blockIdx.x*256 + threadIdx.x;
  if(v<n) dinv[v] = rsqrtf((float)deg[v]);
}
// single-pass scan: per-thread serial chunk + ONE 1024-wide block scan
// (10 barrier rounds total vs 100 in the old 10-chunk version).
__global__ __launch_bounds__(1024) void k_scan(const int* __restrict__ deg,
    int* __restrict__ row_ptr, int* __restrict__ fill, int n){
  __shared__ int lds[1024];
  const int t = threadIdx.x;
  const int per = (n + 1023)/1024;
  int a = t*per, b = a+per; if(b>n) b=n;
  int local=0;
  for(int v=a; v<b; ++v) local += deg[v]-1;
  lds[t]=local;
  __syncthreads();
  for(int off=1; off<1024; off<<=1){
    int x=(t>=off)? lds[t-off]:0;
    __syncthreads();
    lds[t]+=x;
    __syncthreads();
  }
  int run = lds[t]-local;          // exclusive prefix of this chunk
  for(int v=a; v<b; ++v){
    row_ptr[v]=run; fill[v]=run;
    run += deg[v]-1;
  }
  if(t==1023) row_ptr[n]=lds[1023];
}
__global__ void k_fill(const int* __restrict__ src, const int* __restrict__ dst, int E,
                       int* __restrict__ fill, int* __restrict__ ecol){
  int e = blockIdx.x*256 + threadIdx.x;
  if(e<E){
    int d = dst[e];
    int pos = atomicAdd(&fill[d], 1);
    ecol[pos] = src[e];
  }
}

// ---------------- weight prep ----------------
__global__ void k_prep_wb(const float* __restrict__ Wi, const float* __restrict__ Wf,
                          const float* __restrict__ Wo, const float* __restrict__ Wg,
                          __bf16* __restrict__ Wb){
  int idx = blockIdx.x*256 + threadIdx.x;
  if(idx >= 32*6*64*8) return;
  int jj = idx & 7;
  int L  = (idx >> 3) & 63;
  int t  = idx >> 9;
  int kt = t - (t/6)*6, CT = t/6;
  int colj = CT*16 + (L & 15);
  int k    = kt*32 + ((L >> 4) << 3) + jj;
  int gate = colj >> 7, jg = colj & 127;
  const float* W = (gate==0)? Wi : (gate==1)? Wf : (gate==2)? Wo : Wg;
  Wb[idx] = (__bf16)W[jg*192 + k];
}
__global__ void k_prep_w1(const float* __restrict__ W1, float* __restrict__ W1t){
  int idx = blockIdx.x*256 + threadIdx.x;
  if(idx >= 128*256) return;
  int k = idx >> 8, j = idx & 255;
  W1t[idx] = (j<128)? W1[j*256+k] : W1[(j-128)*256+128+k];
}
__global__ void k_prep_wc(const float* __restrict__ Wc, float* __restrict__ Wct){
  int idx = blockIdx.x*256 + threadIdx.x;
  if(idx >= 128*64) return;
  int k = idx/64, j = idx%64;
  Wct[idx] = Wc[j*128+k];
}

// ------- init: zero h (both bufs incl ghost row), c, xs ghost rows --------
__global__ void k_init(unsigned* __restrict__ hpA, unsigned* __restrict__ hpB,
                       float* __restrict__ cbuf, __bf16* __restrict__ xs,
                       int NP, int T){
  int i = blockIdx.x*256 + threadIdx.x;
  if(i < (NP+1)*64){ hpA[i]=0u; hpB[i]=0u; }
  if(i < NP*128) cbuf[i]=0.f;
  if(i < T*64){ int t=i>>6, f=i&63; xs[((size_t)t*(NP+1) + NP)*64 + f] = (__bf16)0.f; }
}

// ---------------- xs = dinv[v] * x, bf16, layout [T][NP+1][64] ------------
// vectorized: 1 thread = 8 elems (32B load, 16B store)  [R1-verified]
__global__ void k_xscale(const float* __restrict__ x, const float* __restrict__ dinv,
                         __bf16* __restrict__ xs, int n, int NP){
  int i = blockIdx.x*256 + threadIdx.x;      // index of 8-float group
  if(i >= n*8) return;
  int t = blockIdx.y;
  float dv = dinv[i>>3];
  const float4* xp = (const float4*)(x + (size_t)t*(size_t)n*64) + (size_t)i*2;
  float4 a = xp[0], b = xp[1];
  bf16x8 o;
  o[0]=(__bf16)(a.x*dv); o[1]=(__bf16)(a.y*dv); o[2]=(__bf16)(a.z*dv); o[3]=(__bf16)(a.w*dv);
  o[4]=(__bf16)(b.x*dv); o[5]=(__bf16)(b.y*dv); o[6]=(__bf16)(b.z*dv); o[7]=(__bf16)(b.w*dv);
  *(bf16x8*)(xs + ((size_t)t*(NP+1))*64 + (size_t)i*8) = o;
}

// ---------------- fused step: EXACT R0 structure (625 blocks x 512 thr, ----
// 8 waves, 16 nodes/block, 2 nodes/wave gather, CT=8g+wv MFMA mapping).
// Only confined change vs R0: fsig/ftanh replace OCML sigmoid/tanh.
__global__ __launch_bounds__(512,5) void k_step(
    const __bf16* __restrict__ xst,        // [NP+1][64] slab for step t
    const unsigned* __restrict__ hp_prev,  // [NP+1][64]
    unsigned* __restrict__ hp_cur,
    float* __restrict__ cbuf,              // [NP][128]
    float* __restrict__ hbuf,              // [NP][128] (written on last step)
    const int* __restrict__ row_ptr, const int* __restrict__ ecol,
    const float* __restrict__ dinv, const __bf16* __restrict__ Wb,
    const float* __restrict__ bi, const float* __restrict__ bf_,
    const float* __restrict__ bo, const float* __restrict__ bg,
    int n, int NP, int last)
{
  __shared__ __align__(16) __bf16 s_a[6*544];
  __shared__ int   s_col[1024];
  __shared__ int   s_deg[16];
  __shared__ int   s_beg[16];
  __shared__ float s_dv[16];
  const int tid=threadIdx.x, wv=tid>>6, l=tid&63;
  const int l15=l&15, quad=l>>4;
  const int v0=blockIdx.x*16;

  if(tid<16){
    int v=v0+tid;
    int beg=(v<n)? row_ptr[v]:0, end=(v<n)? row_ptr[v+1]:0;
    s_beg[tid]=beg; s_deg[tid]=end-beg;
    s_dv[tid]=(v<n)? dinv[v]:0.f;
  }
  __syncthreads();
  for(int idx=tid; idx<1024; idx+=512){
    int m=idx>>6, kk=idx&63;
    s_col[idx]=(kk<s_deg[m])? ecol[s_beg[m]+kk] : NP;   // pad -> zero ghost row
  }
  __syncthreads();

  // ---- phase 1: gather (self + ELL neighbors), 2 nodes per wave ----
  float ax[2], alo[2], ahi[2];
  int K;
  {
    int d0=s_deg[2*wv], d1=s_deg[2*wv+1];
    d0=d0>64?64:d0; d1=d1>64?64:d1;
    K=d0>d1?d0:d1;
  }
  #pragma unroll
  for(int i=0;i<2;++i){
    int v=v0+2*wv+i;
    ax[i]=(float)xst[(size_t)v*64+l];
    unsigned p=hp_prev[(size_t)v*64+l];
    alo[i]=b2f_lo(p); ahi[i]=b2f_hi(p);
  }
  const int* cr=&s_col[(2*wv)*64];
  #pragma unroll 2
  for(int kk=0;kk<K;++kk){
    int u0=cr[kk], u1=cr[64+kk];
    float    x0=(float)xst[(size_t)u0*64+l];
    unsigned p0=hp_prev[(size_t)u0*64+l];
    float    x1=(float)xst[(size_t)u1*64+l];
    unsigned p1=hp_prev[(size_t)u1*64+l];
    ax[0]+=x0; alo[0]+=b2f_lo(p0); ahi[0]+=b2f_hi(p0);
    ax[1]+=x1; alo[1]+=b2f_lo(p1); ahi[1]+=b2f_hi(p1);
  }
  #pragma unroll
  for(int i=0;i<2;++i){              // rare deg>64 overflow
    int m=2*wv+i, d=s_deg[m];
    if(d>64){
      for(int e2=s_beg[m]+64;e2<s_beg[m]+d;++e2){
        int u=ecol[e2];
        ax[i]+=(float)xst[(size_t)u*64+l];
        unsigned p=hp_prev[(size_t)u*64+l];
        alo[i]+=b2f_lo(p); ahi[i]+=b2f_hi(p);
      }
    }
  }
  {
    int kt0=l>>5, q0=(l>>3)&3, j0=l&7;
    int L2=2*l, kt1=2+(L2>>5), q1=(L2>>3)&3, j1=L2&7;
    #pragma unroll
    for(int i=0;i<2;++i){
      int m=2*wv+i; float dv=s_dv[m];
      s_a[kt0*544+q0*136+m*8+j0]=(__bf16)(dv*ax[i]);
      *(unsigned*)&s_a[kt1*544+q1*136+m*8+j1]=f2pk(dv*alo[i],dv*ahi[i]);
    }
  }
  __syncthreads();

  // ---- phase 2: MFMA; wave wv: CT = 8g+wv per gate g ----
  bf16x8 af[6];
  #pragma unroll
  for(int kt=0;kt<6;++kt)
    af[kt]=*(bf16x8*)&s_a[kt*544+quad*136+l15*8];
  const int jg=16*wv+l15;
  floatx4 acc[4];
  {
    #pragma unroll
    for(int g=0;g<4;++g){
      const float* bsel = (g==0)? bi : (g==1)? bf_ : (g==2)? bo : bg;
      float b=bsel[jg];
      floatx4 a={b,b,b,b};
      const __bf16* bp=Wb + (size_t)((8*g+wv)*6)*512 + (size_t)l*8;
      #pragma unroll
      for(int kt=0;kt<6;++kt)
        a=__builtin_amdgcn_mfma_f32_16x16x32_bf16(af[kt],*(const bf16x8*)(bp+kt*512),a,0,0,0);
      acc[g]=a;
    }
  }

  // ---- phase 3: LSTM pointwise in registers (fast transcendentals) ----
  #pragma unroll
  for(int r=0;r<4;++r){
    int m=quad*4+r, v=v0+m;
    float I=fsig (acc[0][r]);
    float F=fsig (acc[1][r]);
    float O=fsig (acc[2][r]);
    float G=ftanh(acc[3][r]);
    size_t coff=(size_t)v*128+jg;
    float cn=F*cbuf[coff]+I*G;
    cbuf[coff]=cn;
    float hn=O*ftanh(cn);
    float hs=s_dv[m]*hn;
    float hs2=__shfl_xor(hs,1,64);
    if((l15&1)==0)
      hp_cur[(size_t)v*64+(jg>>1)]=f2pk(hs,hs2);   // word w = cols {2w,2w+1}
    if(last) hbuf[coff]=hn;
  }
}

// ---------------- head (verified chain) ----------------
__global__ __launch_bounds__(256) void k_head1(const float* __restrict__ h,
    const float* __restrict__ W1t, float* __restrict__ Hio, int n){
  __shared__ float s_h[16][NHID];
  int v0 = blockIdx.x*16;
  for(int i=threadIdx.x; i<16*NHID; i+=256){
    int m = i/NHID, k = i - m*NHID;
    int v = v0 + m;
    s_h[m][k] = (v<n)? h[(size_t)v*NHID + k] : 0.0f;
  }
  __syncthreads();
  int j = threadIdx.x;
  float acc[16];
  #pragma unroll
  for(int m=0;m<16;++m) acc[m]=0.f;
  for(int k=0;k<NHID;++k){
    float w = W1t[k*256 + j];
    #pragma unroll
    for(int m=0;m<16;++m) acc[m] = fmaf(w, s_h[m][k], acc[m]);
  }
  for(int m=0;m<16;++m){
    int v = v0 + m;
    if(v >= n) break;
    Hio[(size_t)v*256 + j] = acc[m];
  }
}
__global__ __launch_bounds__(256) void k_e2n(const float* __restrict__ Hio,
    const int* __restrict__ row_ptr, const int* __restrict__ col,
    const float* __restrict__ b1, float* __restrict__ nodes, int n){
  int wv = threadIdx.x >> 6, lane = threadIdx.x & 63;
  int v = blockIdx.x*4 + wv;
  if(v >= n) return;
  float base0 = Hio[(size_t)v*256 + lane]      + b1[lane];
  float base1 = Hio[(size_t)v*256 + 64 + lane] + b1[64+lane];
  float a0=0.f, a1=0.f;
  int beg=row_ptr[v], end=row_ptr[v+1];
  int e=beg;
  for(; e+1<end; e+=2){          // 2-way unroll: double the loads in flight
    int u0 = col[e], u1 = col[e+1];
    float p0 = Hio[(size_t)u0*256 + 128 + lane];
    float q0 = Hio[(size_t)u0*256 + 192 + lane];
    float p1 = Hio[(size_t)u1*256 + 128 + lane];
    float q1 = Hio[(size_t)u1*256 + 192 + lane];
    a0 += fmaxf(base0 + p0, 0.0f) + fmaxf(base0 + p1, 0.0f);
    a1 += fmaxf(base1 + q0, 0.0f) + fmaxf(base1 + q1, 0.0f);
  }
  if(e<end){
    int u = col[e];
    a0 += fmaxf(base0 + Hio[(size_t)u*256 + 128 + lane], 0.0f);
    a1 += fmaxf(base1 + Hio[(size_t)u*256 + 192 + lane], 0.0f);
  }
  nodes[(size_t)v*NHID + lane]      = a0;
  nodes[(size_t)v*NHID + 64 + lane] = a1;
}
__global__ __launch_bounds__(64) void k_head2(const float* __restrict__ nodes,
    const float* __restrict__ Wct, float* __restrict__ tmp, int n){
  __shared__ float s_n[16][NHID];
  int v0 = blockIdx.x*16;
  for(int i=threadIdx.x; i<16*NHID; i+=64){
    int m = i/NHID, k = i - m*NHID;
    int v = v0 + m;
    s_n[m][k] = (v<n)? nodes[(size_t)v*NHID + k] : 0.0f;
  }
  __syncthreads();
  int j = threadIdx.x;
  float acc[16];
  #pragma unroll
  for(int m=0;m<16;++m) acc[m]=0.f;
  for(int k=0;k<NHID;++k){
    float w = Wct[k*64 + j];
    #pragma unroll
    for(int m=0;m<16;++m) acc[m] = fmaf(w, s_n[m][k], acc[m]);
  }
  for(int m=0;m<16;++m){
    int v = v0 + m;
    if(v >= n) break;
    tmp[(size_t)v*64 + j] = acc[m];
  }
}
__global__ __launch_bounds__(256) void k_final(const float* __restrict__ tmp,
    const int* __restrict__ row_ptr, const int* __restrict__ col,
    const float* __restrict__ dinv, const float* __restrict__ bc,
    float* __restrict__ out, int n){
  int wv = threadIdx.x >> 6, lane = threadIdx.x & 63;
  int v = blockIdx.x*4 + wv;
  if(v >= n) return;
  float dv = dinv[v];
  float acc = dv*dv*tmp[(size_t)v*64 + lane];
  int beg=row_ptr[v], end=row_ptr[v+1];
  int e=beg;
  for(; e+1<end; e+=2){          // 2-way unroll
    int u0 = col[e], u1 = col[e+1];
    float d0 = dinv[u0], d1 = dinv[u1];
    float t0 = tmp[(size_t)u0*64 + lane];
    float t1 = tmp[(size_t)u1*64 + lane];
    acc = fmaf(dv*d0, t0, acc);
    acc = fmaf(dv*d1, t1, acc);
  }
  if(e<end){
    int u = col[e];
    acc = fmaf(dv*dinv[u], tmp[(size_t)u*64 + lane], acc);
  }
  out[(size_t)v*64 + lane] = acc + bc[lane];
}

extern "C" void kernel_launch(void* const* d_in, const int* in_sizes, int n_in,
                              void* d_out, int out_size, void* d_ws, size_t ws_size,
                              hipStream_t stream) {
  (void)n_in; (void)ws_size;
  const float* x  = (const float*)d_in[0];
  const int*   ei = (const int*)d_in[1];
  const float* Wi = (const float*)d_in[4];  const float* bi  = (const float*)d_in[5];
  const float* Wf = (const float*)d_in[6];  const float* bf_ = (const float*)d_in[7];
  const float* Wo = (const float*)d_in[8];  const float* bo  = (const float*)d_in[9];
  const float* Wg = (const float*)d_in[10]; const float* bg  = (const float*)d_in[11];
  const float* W1 = (const float*)d_in[12]; const float* b1  = (const float*)d_in[13];
  const float* Wc = (const float*)d_in[14]; const float* bc  = (const float*)d_in[15];
  float* out = (float*)d_out;

  const int E = in_sizes[2];
  const int n = out_size / NOUT;
  const int T = in_sizes[0] / (n * NIN);
  const int ntiles = (n + 15)/16;
  const int NP = ntiles*16;
  const int* srcl = ei;
  const int* dstl = ei + E;

  char* p = (char*)d_ws;
  auto alloc = [&](size_t bytes){ char* r = p; p += ((bytes + 255)/256)*256; return r; };
  int*      deg     = (int*)     alloc((size_t)n*4);
  float*    dinv    = (float*)   alloc((size_t)n*4);
  int*      row_ptr = (int*)     alloc((size_t)(n+1)*4);
  int*      fill    = (int*)     alloc((size_t)n*4);
  int*      ecol    = (int*)     alloc((size_t)E*4);
  __bf16*   Wb      = (__bf16*)  alloc((size_t)32*6*64*8*2);
  float*    W1t     = (float*)   alloc((size_t)128*256*4);
  float*    Wct     = (float*)   alloc((size_t)128*64*4);
  __bf16*   xs      = (__bf16*)  alloc((size_t)T*(NP+1)*64*2);
  unsigned* hpA     = (unsigned*)alloc((size_t)(NP+1)*64*4);
  unsigned* hpB     = (unsigned*)alloc((size_t)(NP+1)*64*4);
  float*    cbuf    = (float*)   alloc((size_t)NP*128*4);
  float*    hbuf    = (float*)   alloc((size_t)NP*128*4);
  float*    Hio     = (float*)   alloc((size_t)NP*256*4);
  float*    nodes   = (float*)   alloc((size_t)n*NHID*4);
  float*    tmp     = (float*)   alloc((size_t)NP*64*4);

  int gn = (n+255)/256;
  int gE = (E+255)/256;

  k_deg_init <<<gn, 256, 0, stream>>>(deg, n);
  k_deg_count<<<gE, 256, 0, stream>>>(dstl, E, deg);
  k_dinv     <<<gn, 256, 0, stream>>>(deg, dinv, n);
  k_scan     <<<1, 1024, 0, stream>>>(deg, row_ptr, fill, n);
  k_fill     <<<gE, 256, 0, stream>>>(srcl, dstl, E, fill, ecol);

  k_prep_wb<<<(32*6*64*8+255)/256, 256, 0, stream>>>(Wi, Wf, Wo, Wg, Wb);
  k_prep_w1<<<(128*256+255)/256, 256, 0, stream>>>(W1, W1t);
  k_prep_wc<<<(128*64+255)/256, 256, 0, stream>>>(Wc, Wct);

  k_init<<<((NP*128)+255)/256, 256, 0, stream>>>(hpA, hpB, cbuf, xs, NP, T);
  k_xscale<<<dim3((n*8+255)/256, T), 256, 0, stream>>>(x, dinv, xs, n, NP);

  for(int t=0; t<T; ++t){
    const __bf16* xst = xs + (size_t)t*(size_t)(NP+1)*64;
    const unsigned* hp = (t & 1)? hpB : hpA;
    unsigned*       hc = (t & 1)? hpA : hpB;
    k_step<<<ntiles, 512, 0, stream>>>(xst, hp, hc, cbuf, hbuf, row_ptr, ecol, dinv,
                                       Wb, bi, bf_, bo, bg, n, NP, (t==T-1)?1:0);
  }

  k_head1<<<ntiles, 256, 0, stream>>>(hbuf, W1t, Hio, n);
  k_e2n  <<<(n+3)/4, 256, 0, stream>>>(Hio, row_ptr, ecol, b1, nodes, n);
  k_head2<<<(n+15)/16, 64, 0, stream>>>(nodes, Wct, tmp, n);
  k_final<<<(n+3)/4, 256, 0, stream>>>(tmp, row_ptr, ecol, dinv, bc, out, n);
}